// Round 1
// baseline (15641.281 us; speedup 1.0000x reference)
//
#include <hip/hip_runtime.h>
#include <stdint.h>

#define TSTEPS 2048
#define NB     16
#define HDIM   500
#define HPAD   512
#define NSLICE 16
#define NTHR   256

typedef __attribute__((ext_vector_type(8))) short s16x8;
typedef __attribute__((ext_vector_type(4))) float f32x4;

__device__ __forceinline__ unsigned short f2bf(float f) {
    unsigned u = __float_as_uint(f);
    u += 0x7FFFu + ((u >> 16) & 1u);     // RNE to bf16
    return (unsigned short)(u >> 16);
}
__device__ __forceinline__ float bflo(uint32_t v) { return __uint_as_float(v << 16); }
__device__ __forceinline__ float bfhi(uint32_t v) { return __uint_as_float(v & 0xFFFF0000u); }
__device__ __forceinline__ float sigm(float x)   { return __fdividef(1.f, 1.f + __expf(-x)); }
__device__ __forceinline__ float tanhf_(float x) { return 1.f - __fdividef(2.f, __expf(2.f * x) + 1.f); }

__global__ void zero_ws_kernel(uint32_t* p, int n) {
    int i = blockIdx.x * blockDim.x + threadIdx.x;
    if (i < n) p[i] = 0u;
}

__global__ __launch_bounds__(NTHR, 1) void wavernn_persist(
    const float* __restrict__ mgc,  const float* __restrict__ eps,
    const float* __restrict__ Wup,  const float* __restrict__ bup,
    const float* __restrict__ Wih,  const float* __restrict__ Whh,
    const float* __restrict__ bih,  const float* __restrict__ bhh,
    const float* __restrict__ Wout, const float* __restrict__ bout,
    float* __restrict__ out, uint32_t* __restrict__ hbuf, uint32_t* __restrict__ seq)
{
    const int s    = blockIdx.x;       // h-slice: elems [s*32, s*32+32)
    const int tid  = threadIdx.x;
    const int lane = tid & 63;
    const int wave = tid >> 6;         // wave == gate type (i,f,g,o)
    const int l16  = lane & 15;
    const int g    = lane >> 4;

    __shared__ __align__(16) uint32_t h_sw[HPAD * NB / 2]; // bf16 h(t-1/t), XOR-swizzled
    __shared__ __align__(16) float gates_l[NB * 128];      // [b][n]
    __shared__ __align__(16) float gcond[128 * NB];        // [n][b] per-frame gate bias
    __shared__ __align__(16) float condT[256 * NB];        // [c][b]
    __shared__ __align__(16) float mgcl[NB * 80];
    __shared__ __align__(16) float woutl[2 * HPAD];
    __shared__ __align__(16) float zz_l[NB];
    __shared__ __align__(16) float red[NB * 2 * 8 + NB * 2];

    // ---- register-resident W_hh bf16 B-fragments: 2 tiles x 16 K-steps = 128 VGPR/lane ----
    s16x8 bfr[2][16];
    float wihl[2];
    #pragma unroll
    for (int t2 = 0; t2 < 2; ++t2) {
        const int q    = t2 * 16 + l16;       // 0..31 within slice
        const int hidx = s * 32 + q;
        const bool valid = hidx < HDIM;
        const int grow = wave * HDIM + hidx;  // global gate row
        wihl[t2] = valid ? Wih[grow * 257 + 256] : 0.f;
        #pragma unroll
        for (int kk = 0; kk < 16; ++kk) {
            const int k0 = kk * 32 + g * 8;
            s16x8 r;
            #pragma unroll
            for (int j = 0; j < 8; ++j) {
                const int k = k0 + j;
                const float v = (valid && k < HDIM) ? Whh[grow * HDIM + k] : 0.f;
                r[j] = (short)f2bf(v);
            }
            bfr[t2][kk] = r;
        }
    }
    for (int i = tid; i < 2 * HPAD; i += NTHR) {
        const int j = i >> 9, k = i & (HPAD - 1);
        woutl[i] = (k < HDIM) ? Wout[j * HDIM + k] : 0.f;
    }
    for (int i = tid; i < HPAD * NB / 2; i += NTHR) h_sw[i] = 0u;  // h(-1) = 0
    if (tid < NB) zz_l[tid] = 0.f;                                 // zz(-1) = 0

    float cst0 = 0.f, cst1 = 0.f;   // c-state for (b_e, 2*qh), (b_e, 2*qh+1)
    const int b_e = tid >> 4;
    const int qh  = tid & 15;
    __syncthreads();

    for (int t = 0; t < TSTEPS; ++t) {
        if ((t & 63) == 0) {   // new frame: rebuild gcond = bias + cond @ Wih[:, :256]^T
            const int f = t >> 6;
            for (int i = tid; i < NB * 80; i += NTHR) {
                const int b = i / 80, m = i - b * 80;
                mgcl[i] = mgc[(b * 32 + f) * 80 + m];
            }
            __syncthreads();
            {   // condT[c][b] = b_up[c] + mgc[b] @ Wup[:,c]
                const int c = tid;
                float a[NB];
                #pragma unroll
                for (int b = 0; b < NB; ++b) a[b] = bup[c];
                for (int m = 0; m < 80; ++m) {
                    const float w = Wup[m * 256 + c];
                    #pragma unroll
                    for (int b = 0; b < NB; ++b) a[b] += mgcl[b * 80 + m] * w;
                }
                #pragma unroll
                for (int b = 0; b < NB; ++b) condT[c * NB + b] = a[b];
            }
            __syncthreads();
            {   // gcond[n][b]
                const int n = tid >> 1, kc = tid & 1;
                const int gate = n >> 5, q = n & 31;
                const int hidx = s * 32 + q;
                const bool valid = hidx < HDIM;
                const int grow = gate * HDIM + hidx;
                float a[NB];
                #pragma unroll
                for (int b = 0; b < NB; ++b) a[b] = 0.f;
                if (valid) {
                    const float* wr = Wih + (size_t)grow * 257 + kc * 128;
                    for (int k = 0; k < 128; ++k) {
                        const float w = wr[k];
                        const float* cp = &condT[(kc * 128 + k) * NB];
                        #pragma unroll
                        for (int b = 0; b < NB; ++b) a[b] += cp[b] * w;
                    }
                }
                if (kc == 0) {
                    const float bias = valid ? (bih[grow] + bhh[grow]) : 0.f;
                    #pragma unroll
                    for (int b = 0; b < NB; ++b) gcond[n * NB + b] = a[b] + bias;
                }
                __syncthreads();
                if (kc == 1) {
                    #pragma unroll
                    for (int b = 0; b < NB; ++b) gcond[n * NB + b] += a[b];
                }
            }
            __syncthreads();
        }

        // ---- phase 1: gates = gcond + zz_prev * w_x + h(t-1) @ Whh^T  (MFMA) ----
        const int n0 = wave * 32 + l16;
        f32x4 acc0, acc1;
        {
            const f32x4 gc0 = *(const f32x4*)&gcond[n0 * NB + g * 4];
            const f32x4 gc1 = *(const f32x4*)&gcond[(n0 + 16) * NB + g * 4];
            const f32x4 zz4 = *(const f32x4*)&zz_l[g * 4];
            acc0 = gc0 + zz4 * wihl[0];
            acc1 = gc1 + zz4 * wihl[1];
        }
        #pragma unroll
        for (int kk = 0; kk < 16; ++kk) {
            const int off = (l16 * 1024 + kk * 64 + g * 16) ^ ((l16 & 7) << 4);
            const s16x8 a = *(const s16x8*)((const char*)h_sw + off);
            acc0 = __builtin_amdgcn_mfma_f32_16x16x32_bf16(a, bfr[0][kk], acc0, 0, 0, 0);
            acc1 = __builtin_amdgcn_mfma_f32_16x16x32_bf16(a, bfr[1][kk], acc1, 0, 0, 0);
        }
        #pragma unroll
        for (int v = 0; v < 4; ++v) {   // D: batch=(lane>>4)*4+v, n=lane&15 (+16)
            gates_l[(g * 4 + v) * 128 + n0]      = acc0[v];
            gates_l[(g * 4 + v) * 128 + n0 + 16] = acc1[v];
        }
        __syncthreads();

        // ---- phase 2: LSTM cell, publish h(t) slice ----
        {
            const int q0 = 2 * qh, q1 = q0 + 1;
            uint32_t hp = 0;
            {
                const float gi = gates_l[b_e * 128 +      q0];
                const float gf = gates_l[b_e * 128 + 32 + q0];
                const float gg = gates_l[b_e * 128 + 64 + q0];
                const float go = gates_l[b_e * 128 + 96 + q0];
                cst0 = sigm(gf) * cst0 + sigm(gi) * tanhf_(gg);
                const float h = sigm(go) * tanhf_(cst0);
                if (s * 32 + q0 < HDIM) hp |= (uint32_t)f2bf(h);
            }
            {
                const float gi = gates_l[b_e * 128 +      q1];
                const float gf = gates_l[b_e * 128 + 32 + q1];
                const float gg = gates_l[b_e * 128 + 64 + q1];
                const float go = gates_l[b_e * 128 + 96 + q1];
                cst1 = sigm(gf) * cst1 + sigm(gi) * tanhf_(gg);
                const float h = sigm(go) * tanhf_(cst1);
                if (s * 32 + q1 < HDIM) hp |= ((uint32_t)f2bf(h)) << 16;
            }
            __hip_atomic_store(&hbuf[(t & 1) * 4096 + b_e * 256 + s * 16 + qh], hp,
                               __ATOMIC_RELAXED, __HIP_MEMORY_SCOPE_AGENT);
        }
        __syncthreads();   // drains stores (vmcnt 0) before flag

        if (tid == 0)
            __hip_atomic_store(&seq[s * 32], (uint32_t)(t + 1),
                               __ATOMIC_RELEASE, __HIP_MEMORY_SCOPE_AGENT);
        if (tid < NSLICE) {
            int guard = 0;
            while (__hip_atomic_load(&seq[tid * 32], __ATOMIC_ACQUIRE,
                                     __HIP_MEMORY_SCOPE_AGENT) < (uint32_t)(t + 1)) {
                if (++guard > (1 << 19)) break;
            }
        }
        __syncthreads();

        // ---- phase 4: gather full h(t) into LDS (swizzled bf16) ----
        #pragma unroll
        for (int it = 0; it < 16; ++it) {
            const uint32_t hv = __hip_atomic_load(&hbuf[(t & 1) * 4096 + it * 256 + tid],
                                                  __ATOMIC_RELAXED, __HIP_MEMORY_SCOPE_AGENT);
            const int byte = (it * 1024 + tid * 4) ^ ((it & 7) << 4);
            *(uint32_t*)((char*)h_sw + byte) = hv;
        }
        __syncthreads();

        // ---- phase 5: out = h(t) @ Wout^T; mean/logvar/zz; zz feeds t+1 ----
        {
            const int b = tid & 15, jj = (tid >> 4) & 1, ch = tid >> 5;
            float a = 0.f;
            #pragma unroll 8
            for (int i = 0; i < 32; ++i) {
                const int kp = ch * 32 + i;
                const int byte = (b * 1024 + kp * 4) ^ ((b & 7) << 4);
                const uint32_t h2 = *(const uint32_t*)((const char*)h_sw + byte);
                const float2 wv = *(const float2*)&woutl[jj * HPAD + kp * 2];
                a += bflo(h2) * wv.x + bfhi(h2) * wv.y;
            }
            red[(b * 2 + jj) * 8 + ch] = a;
        }
        __syncthreads();
        if (tid < 32) {
            float a = 0.f;
            #pragma unroll
            for (int i = 0; i < 8; ++i) a += red[tid * 8 + i];
            red[256 + tid] = a;
        }
        __syncthreads();
        if (tid < NB) {
            const float o0 = red[256 + tid * 2]     + bout[0];
            const float o1 = red[256 + tid * 2 + 1] + bout[1];
            const float mean = tanhf_(o0);
            const float lv   = fmaxf(o1, -7.f);
            const float zzv  = mean + eps[tid * 2048 + t] * __expf(lv);
            zz_l[tid] = zzv;
            if (s == 0) {
                out[         tid * 2048 + t] = mean;
                out[32768 +  tid * 2048 + t] = lv;
                out[65536 +  tid * 2048 + t] = zzv;
            }
        }
        __syncthreads();
    }
}

extern "C" void kernel_launch(void* const* d_in, const int* in_sizes, int n_in,
                              void* d_out, int out_size, void* d_ws, size_t ws_size,
                              hipStream_t stream) {
    const float* mgc  = (const float*)d_in[0];
    const float* eps  = (const float*)d_in[1];
    const float* Wup  = (const float*)d_in[2];
    const float* bup  = (const float*)d_in[3];
    const float* Wih  = (const float*)d_in[4];
    const float* Whh  = (const float*)d_in[5];
    const float* bih  = (const float*)d_in[6];
    const float* bhh  = (const float*)d_in[7];
    const float* Wout = (const float*)d_in[8];
    const float* bout = (const float*)d_in[9];

    uint32_t* hbuf = (uint32_t*)d_ws;   // 2 x 4096 u32 (double-buffered bf16 h)
    uint32_t* seq  = hbuf + 8192;       // 16 flags, 128B stride

    zero_ws_kernel<<<34, 256, 0, stream>>>(hbuf, 8192 + 512);
    wavernn_persist<<<NSLICE, NTHR, 0, stream>>>(mgc, eps, Wup, bup, Wih, Whh,
                                                 bih, bhh, Wout, bout,
                                                 (float*)d_out, hbuf, seq);
}

// Round 2
// 9344.862 us; speedup vs baseline: 1.6738x; 1.6738x over previous
//
#include <hip/hip_runtime.h>
#include <stdint.h>

#define TSTEPS 2048
#define NB     16
#define HDIM   500
#define HPAD   512
#define NSLICE 16
#define NTHR   256
#define RECU32 320                 // per-WG record: 256 u32 h + 32 u32 partials + pad

typedef __attribute__((ext_vector_type(8))) short s16x8;
typedef __attribute__((ext_vector_type(4))) float f32x4;

__device__ __forceinline__ unsigned short f2bf(float f) {
    unsigned u = __float_as_uint(f);
    u += 0x7FFFu + ((u >> 16) & 1u);
    return (unsigned short)(u >> 16);
}
__device__ __forceinline__ float sigm(float x)   { return __fdividef(1.f, 1.f + __expf(-x)); }
__device__ __forceinline__ float tanhf_(float x) { return 1.f - __fdividef(2.f, __expf(2.f * x) + 1.f); }

__global__ void zero_ws_kernel(uint32_t* p, int n) {
    int i = blockIdx.x * blockDim.x + threadIdx.x;
    if (i < n) p[i] = 0u;
}

__global__ __launch_bounds__(NTHR, 1) void wavernn_persist(
    const float* __restrict__ mgc,  const float* __restrict__ eps,
    const float* __restrict__ Wup,  const float* __restrict__ bup,
    const float* __restrict__ Wih,  const float* __restrict__ Whh,
    const float* __restrict__ bih,  const float* __restrict__ bhh,
    const float* __restrict__ Wout, const float* __restrict__ bout,
    float* __restrict__ out, uint32_t* __restrict__ hbuf, uint32_t* __restrict__ seq)
{
    const int s    = blockIdx.x;
    const int tid  = threadIdx.x;
    const int lane = tid & 63;
    const int wave = tid >> 6;         // wave == gate type (i,f,g,o)
    const int l16  = lane & 15;
    const int g    = lane >> 4;

    __shared__ __align__(16) uint32_t h_sw[HPAD * NB / 2]; // 16KB swizzled bf16 h
    __shared__ __align__(16) float gates_l[NB * 132];
    __shared__ __align__(16) float gcond[128 * NB];        // [n][b]
    __shared__ __align__(16) float condT[256 * NB];        // [c][b]
    __shared__ __align__(16) float mgcl[NB * 80];
    __shared__ __align__(16) float eps_l[64 * NB];         // [step_in_frame][b]

    // ---- register-resident W_hh bf16 B-fragments ----
    s16x8 bfr[2][16];
    float wihl[2];
    #pragma unroll
    for (int t2 = 0; t2 < 2; ++t2) {
        const int q    = t2 * 16 + l16;
        const int hidx = s * 32 + q;
        const bool valid = hidx < HDIM;
        const int grow = wave * HDIM + hidx;
        wihl[t2] = valid ? Wih[grow * 257 + 256] : 0.f;
        #pragma unroll
        for (int kk = 0; kk < 16; ++kk) {
            const int k0 = kk * 32 + g * 8;
            s16x8 r;
            #pragma unroll
            for (int j = 0; j < 8; ++j) {
                const int k = k0 + j;
                const float v = (valid && k < HDIM) ? Whh[grow * HDIM + k] : 0.f;
                r[j] = (short)f2bf(v);
            }
            bfr[t2][kk] = r;
        }
    }
    // cell-thread roles & constants
    const int b_e = tid >> 4;
    const int qh  = tid & 15;
    const int q0  = 2 * qh, q1 = q0 + 1;
    const int k0g = s * 32 + q0, k1g = s * 32 + q1;
    const float w0q0 = (k0g < HDIM) ? Wout[k0g]        : 0.f;
    const float w0q1 = (k1g < HDIM) ? Wout[k1g]        : 0.f;
    const float w1q0 = (k0g < HDIM) ? Wout[HDIM + k0g] : 0.f;
    const float w1q1 = (k1g < HDIM) ? Wout[HDIM + k1g] : 0.f;
    const float bout0 = bout[0], bout1 = bout[1];
    float cst0 = 0.f, cst1 = 0.f;

    for (int t = 0; t < TSTEPS; ++t) {
        // ---- a) spin (all waves, relaxed) for h(t-1): flags >= t ----
        if (t > 0) {
            int guard = 0;
            while (__hip_atomic_load(&seq[(tid & 15) * 32], __ATOMIC_RELAXED,
                                     __HIP_MEMORY_SCOPE_AGENT) < (uint32_t)t) {
                if (++guard > (1 << 20)) break;
            }
        }
        __threadfence();   // acquire: invalidate L1/L2 so plain loads see LLC data

        // ---- b) gather h(t-1) into swizzled LDS + compute zz(t-1) ----
        {
            const int b = tid >> 4, p = tid & 15;
            const uint32_t gbase = (uint32_t)((((t & 1) ^ 1) * 16 + p) * RECU32 + b * 16);
            const uint4* srcp = (const uint4*)&hbuf[gbase];
            uint4 v0 = srcp[0], v1 = srcp[1], v2 = srcp[2], v3 = srcp[3];
            const int sw = (b & 7) << 4;
            char* hb = (char*)h_sw;
            *(uint4*)(hb + ((b * 1024 + p * 64 +  0) ^ sw)) = v0;
            *(uint4*)(hb + ((b * 1024 + p * 64 + 16) ^ sw)) = v1;
            *(uint4*)(hb + ((b * 1024 + p * 64 + 32) ^ sw)) = v2;
            *(uint4*)(hb + ((b * 1024 + p * 64 + 48) ^ sw)) = v3;
        }
        float zzv = 0.f, mean = 0.f, lv = 0.f;
        {
            const int b = tid & 15;
            float o0 = bout0, o1 = bout1;
            #pragma unroll
            for (int j = 0; j < 16; ++j) {
                const float2 pp = *(const float2*)&hbuf[(((t & 1) ^ 1) * 16 + j) * RECU32 + 256 + b * 2];
                o0 += pp.x; o1 += pp.y;
            }
            if (t > 0) {
                mean = tanhf_(o0);
                lv   = fmaxf(o1, -7.f);
                zzv  = mean + eps_l[((t - 1) & 63) * NB + b] * __expf(lv);
            }
        }
        if (s == 0 && t > 0 && tid < 16) {
            out[         tid * 2048 + (t - 1)] = mean;
            out[32768 +  tid * 2048 + (t - 1)] = lv;
            out[65536 +  tid * 2048 + (t - 1)] = zzv;
        }
        __syncthreads();

        // ---- d) per-frame: gcond rebuild + eps chunk ----
        if ((t & 63) == 0) {
            const int f = t >> 6;
            for (int i = tid; i < NB * 80; i += NTHR) {
                const int b = i / 80, m = i - b * 80;
                mgcl[i] = mgc[(b * 32 + f) * 80 + m];
            }
            for (int i = tid; i < 64 * NB; i += NTHR) {
                const int st = i >> 4, b = i & 15;
                eps_l[i] = eps[b * 2048 + f * 64 + st];
            }
            __syncthreads();
            {
                const int c = tid;
                float a[NB];
                #pragma unroll
                for (int b = 0; b < NB; ++b) a[b] = bup[c];
                for (int m = 0; m < 80; ++m) {
                    const float w = Wup[m * 256 + c];
                    #pragma unroll
                    for (int b = 0; b < NB; ++b) a[b] += mgcl[b * 80 + m] * w;
                }
                #pragma unroll
                for (int b = 0; b < NB; ++b) condT[c * NB + b] = a[b];
            }
            __syncthreads();
            {
                const int n = tid >> 1, kc = tid & 1;
                const int gate = n >> 5, q = n & 31;
                const int hidx = s * 32 + q;
                const bool valid = hidx < HDIM;
                const int grow = gate * HDIM + hidx;
                float a[NB];
                #pragma unroll
                for (int b = 0; b < NB; ++b) a[b] = 0.f;
                if (valid) {
                    const float* wr = Wih + (size_t)grow * 257 + kc * 128;
                    for (int k = 0; k < 128; ++k) {
                        const float w = wr[k];
                        const float* cp = &condT[(kc * 128 + k) * NB];
                        #pragma unroll
                        for (int b = 0; b < NB; ++b) a[b] += cp[b] * w;
                    }
                }
                if (kc == 0) {
                    const float bias = valid ? (bih[grow] + bhh[grow]) : 0.f;
                    #pragma unroll
                    for (int b = 0; b < NB; ++b) gcond[n * NB + b] = a[b] + bias;
                }
                __syncthreads();
                if (kc == 1) {
                    #pragma unroll
                    for (int b = 0; b < NB; ++b) gcond[n * NB + b] += a[b];
                }
            }
            __syncthreads();
        }

        // ---- e) MFMA: gates = gcond + zz*w_x + h @ Whh^T ----
        const int n0 = wave * 32 + l16;
        f32x4 acc0a = *(const f32x4*)&gcond[n0 * NB + g * 4];
        f32x4 acc1a = *(const f32x4*)&gcond[(n0 + 16) * NB + g * 4];
        f32x4 acc0b = {0.f, 0.f, 0.f, 0.f};
        f32x4 acc1b = {0.f, 0.f, 0.f, 0.f};
        #pragma unroll
        for (int kk = 0; kk < 8; ++kk) {
            const int off0 = (l16 * 1024 + kk * 64 + g * 16) ^ ((l16 & 7) << 4);
            const int off1 = (l16 * 1024 + (kk + 8) * 64 + g * 16) ^ ((l16 & 7) << 4);
            const s16x8 a0 = *(const s16x8*)((const char*)h_sw + off0);
            const s16x8 a1 = *(const s16x8*)((const char*)h_sw + off1);
            acc0a = __builtin_amdgcn_mfma_f32_16x16x32_bf16(a0, bfr[0][kk],     acc0a, 0, 0, 0);
            acc1a = __builtin_amdgcn_mfma_f32_16x16x32_bf16(a0, bfr[1][kk],     acc1a, 0, 0, 0);
            acc0b = __builtin_amdgcn_mfma_f32_16x16x32_bf16(a1, bfr[0][kk + 8], acc0b, 0, 0, 0);
            acc1b = __builtin_amdgcn_mfma_f32_16x16x32_bf16(a1, bfr[1][kk + 8], acc1b, 0, 0, 0);
        }
        {
            f32x4 zzt;
            zzt[0] = __shfl(zzv, g * 4 + 0);
            zzt[1] = __shfl(zzv, g * 4 + 1);
            zzt[2] = __shfl(zzv, g * 4 + 2);
            zzt[3] = __shfl(zzv, g * 4 + 3);
            const f32x4 r0 = acc0a + acc0b + zzt * wihl[0];
            const f32x4 r1 = acc1a + acc1b + zzt * wihl[1];
            #pragma unroll
            for (int v = 0; v < 4; ++v) {
                gates_l[(g * 4 + v) * 132 + n0]      = r0[v];
                gates_l[(g * 4 + v) * 132 + n0 + 16] = r1[v];
            }
        }
        __syncthreads();

        // ---- f) LSTM cell + publish h slice & out-head partials ----
        {
            float po0, po1;
            uint32_t hp = 0;
            {
                const float gi = gates_l[b_e * 132 +      q0];
                const float gf = gates_l[b_e * 132 + 32 + q0];
                const float gg = gates_l[b_e * 132 + 64 + q0];
                const float go = gates_l[b_e * 132 + 96 + q0];
                cst0 = sigm(gf) * cst0 + sigm(gi) * tanhf_(gg);
                const float h = sigm(go) * tanhf_(cst0);
                if (k0g < HDIM) hp |= (uint32_t)f2bf(h);
                po0 = h * w0q0; po1 = h * w1q0;
            }
            {
                const float gi = gates_l[b_e * 132 +      q1];
                const float gf = gates_l[b_e * 132 + 32 + q1];
                const float gg = gates_l[b_e * 132 + 64 + q1];
                const float go = gates_l[b_e * 132 + 96 + q1];
                cst1 = sigm(gf) * cst1 + sigm(gi) * tanhf_(gg);
                const float h = sigm(go) * tanhf_(cst1);
                if (k1g < HDIM) hp |= ((uint32_t)f2bf(h)) << 16;
                po0 += h * w0q1; po1 += h * w1q1;
            }
            const uint32_t rbase = (uint32_t)(((t & 1) * 16 + s) * RECU32);
            __hip_atomic_store(&hbuf[rbase + b_e * 16 + qh], hp,
                               __ATOMIC_RELAXED, __HIP_MEMORY_SCOPE_AGENT);
            po0 += __shfl_xor(po0, 1);  po1 += __shfl_xor(po1, 1);
            po0 += __shfl_xor(po0, 2);  po1 += __shfl_xor(po1, 2);
            po0 += __shfl_xor(po0, 4);  po1 += __shfl_xor(po1, 4);
            po0 += __shfl_xor(po0, 8);  po1 += __shfl_xor(po1, 8);
            if (qh == 0) {
                const uint64_t pk = (uint64_t)__float_as_uint(po0) |
                                    ((uint64_t)__float_as_uint(po1) << 32);
                __hip_atomic_store((uint64_t*)&hbuf[rbase + 256 + b_e * 2], pk,
                                   __ATOMIC_RELAXED, __HIP_MEMORY_SCOPE_AGENT);
            }
        }
        __syncthreads();   // drain stores before flag
        if (tid == 0)
            __hip_atomic_store(&seq[s * 32], (uint32_t)(t + 1),
                               __ATOMIC_RELEASE, __HIP_MEMORY_SCOPE_AGENT);
    }

    // ---- epilogue: out(2047) ----
    if (s == 0) {
        if (tid < 16) {
            int guard = 0;
            while (__hip_atomic_load(&seq[tid * 32], __ATOMIC_RELAXED,
                                     __HIP_MEMORY_SCOPE_AGENT) < (uint32_t)TSTEPS) {
                if (++guard > (1 << 20)) break;
            }
        }
        __syncthreads();
        __threadfence();
        if (tid < 16) {
            float o0 = bout0, o1 = bout1;
            #pragma unroll
            for (int j = 0; j < 16; ++j) {
                const float2 pp = *(const float2*)&hbuf[(16 + j) * RECU32 + 256 + tid * 2];
                o0 += pp.x; o1 += pp.y;
            }
            const float mean = tanhf_(o0);
            const float lvv  = fmaxf(o1, -7.f);
            const float zzv  = mean + eps_l[63 * NB + tid] * __expf(lvv);
            out[         tid * 2048 + 2047] = mean;
            out[32768 +  tid * 2048 + 2047] = lvv;
            out[65536 +  tid * 2048 + 2047] = zzv;
        }
    }
}

extern "C" void kernel_launch(void* const* d_in, const int* in_sizes, int n_in,
                              void* d_out, int out_size, void* d_ws, size_t ws_size,
                              hipStream_t stream) {
    const float* mgc  = (const float*)d_in[0];
    const float* eps  = (const float*)d_in[1];
    const float* Wup  = (const float*)d_in[2];
    const float* bup  = (const float*)d_in[3];
    const float* Wih  = (const float*)d_in[4];
    const float* Whh  = (const float*)d_in[5];
    const float* bih  = (const float*)d_in[6];
    const float* bhh  = (const float*)d_in[7];
    const float* Wout = (const float*)d_in[8];
    const float* bout = (const float*)d_in[9];

    uint32_t* hbuf = (uint32_t*)d_ws;          // 32 records x 320 u32
    uint32_t* seq  = hbuf + 32 * RECU32;       // 16 flags, 128B stride

    zero_ws_kernel<<<42, 256, 0, stream>>>(hbuf, 32 * RECU32 + 512);
    wavernn_persist<<<NSLICE, NTHR, 0, stream>>>(mgc, eps, Wup, bup, Wih, Whh,
                                                 bih, bhh, Wout, bout,
                                                 (float*)d_out, hbuf, seq);
}